// Round 13
// baseline (231.136 us; speedup 1.0000x reference)
//
#include <hip/hip_runtime.h>

// ConvAttention2d: B=4, DIM=384, HEADS=8, DH=64, INNER=512, H=W=56, KS=3
// fp32 in/out. bf16 MFMA GEMMs (fp32 accum), blocked bf16 buffers.
// R13 = R11 (best, 145.5us) + ONE change: BK=64 in both GEMMs (half the
// barriers; K-order kb-ascending preserved -> bit-exact vs R11).

#define HW 3136
#define WIMG 56
#define QKV_CH 1536
#define SCALE 0.125f
#define SLEN 200   // natt LDS row stride (ushorts)

typedef __bf16 bf16x8_t __attribute__((ext_vector_type(8)));
typedef float f32x4_t __attribute__((ext_vector_type(4)));

__device__ __forceinline__ float bf2f(unsigned short u) {
    return __uint_as_float(((unsigned int)u) << 16);
}
__device__ __forceinline__ unsigned short f2bf(float f) {
    unsigned int u = __float_as_uint(f);
    u += 0x7FFFu + ((u >> 16) & 1u);   // round-to-nearest-even
    return (unsigned short)(u >> 16);
}

// ---------------------------------------------------------------------------
// Weights f32 -> bf16, blocked: wT[oblk12][kb12][128o][32k] (Wq||Wkv),
// wT3[oblk3][kb16][128o][32k] (Wo). 98304 threads = exactly 384 blocks.
// ---------------------------------------------------------------------------
__global__ __launch_bounds__(256) void cvt_w(
    const float* __restrict__ Wq, const float* __restrict__ Wkv,
    const float* __restrict__ Wo,
    unsigned short* __restrict__ wT, unsigned short* __restrict__ wT3)
{
    const int i = blockIdx.x * 256 + threadIdx.x;
    if (i < 73728) {                    // wT: 12*12*128*4 uint4 slots
        const int g = i & 3;
        const int idx3 = i >> 2;
        const int o128 = idx3 & 127;
        const int rest = idx3 >> 7;
        const int kb = rest % 12, oblk = rest / 12;
        const int o = oblk * 128 + o128;
        const int k0 = kb * 32 + g * 8;
        const float* src = (o < 512) ? (Wq + (size_t)o * 384 + k0)
                                     : (Wkv + (size_t)(o - 512) * 384 + k0);
        const float4 v0 = *reinterpret_cast<const float4*>(src);
        const float4 v1 = *reinterpret_cast<const float4*>(src + 4);
        uint4 u;
        u.x = (unsigned int)f2bf(v0.x) | ((unsigned int)f2bf(v0.y) << 16);
        u.y = (unsigned int)f2bf(v0.z) | ((unsigned int)f2bf(v0.w) << 16);
        u.z = (unsigned int)f2bf(v1.x) | ((unsigned int)f2bf(v1.y) << 16);
        u.w = (unsigned int)f2bf(v1.z) | ((unsigned int)f2bf(v1.w) << 16);
        reinterpret_cast<uint4*>(wT)[i] = u;
    } else {                            // wT3: 3*16*128*4 = 24576 uint4 slots
        const int j = i - 73728;
        const int g = j & 3;
        const int idx3 = j >> 2;
        const int o128 = idx3 & 127;
        const int rest = idx3 >> 7;
        const int kb = rest % 16, oblk = rest / 16;
        const int o = oblk * 128 + o128;
        const float* src = Wo + (size_t)o * 512 + kb * 32 + g * 8;
        const float4 v0 = *reinterpret_cast<const float4*>(src);
        const float4 v1 = *reinterpret_cast<const float4*>(src + 4);
        uint4 u;
        u.x = (unsigned int)f2bf(v0.x) | ((unsigned int)f2bf(v0.y) << 16);
        u.y = (unsigned int)f2bf(v0.z) | ((unsigned int)f2bf(v0.w) << 16);
        u.z = (unsigned int)f2bf(v1.x) | ((unsigned int)f2bf(v1.y) << 16);
        u.w = (unsigned int)f2bf(v1.z) | ((unsigned int)f2bf(v1.w) << 16);
        reinterpret_cast<uint4*>(wT3)[j] = u;
    }
}

// ---------------------------------------------------------------------------
// x (b,c,s) f32 -> blocked bf16 xT[b][sblk25][kb12][128s][32k], s padded to
// 3200 (tail zero-filled). grid (50,12,4).
// ---------------------------------------------------------------------------
__global__ __launch_bounds__(256) void cvtT_x(
    const float* __restrict__ x, unsigned short* __restrict__ xT)
{
    __shared__ unsigned short Tl[64 * 36];
    const int sblk = blockIdx.x, kblk = blockIdx.y, b = blockIdx.z;
    const int t = threadIdx.x;

    if (sblk == 49) {                   // zero-fill s in [3136,3200)
        unsigned short* dst = xT + (((size_t)b * 25 + 24) * 12 + kblk) * 4096 + 2048;
        *reinterpret_cast<uint4*>(dst + t * 8) = (uint4){0, 0, 0, 0};
        return;
    }

    const float* xp = x + ((size_t)b * 384 + (size_t)kblk * 32) * HW + sblk * 64;
    const int c = t >> 3;
#pragma unroll
    for (int i = 0; i < 2; i++) {
        const int sc = (t & 7) + 8 * i;
        const float4 v = *reinterpret_cast<const float4*>(xp + (size_t)c * HW + sc * 4);
        const int s4 = sc * 4;
        Tl[(s4 + 0) * 36 + c] = f2bf(v.x);
        Tl[(s4 + 1) * 36 + c] = f2bf(v.y);
        Tl[(s4 + 2) * 36 + c] = f2bf(v.z);
        Tl[(s4 + 3) * 36 + c] = f2bf(v.w);
    }
    __syncthreads();

    const int row = t >> 2, gran = t & 3;
    const uint2 lo = *reinterpret_cast<const uint2*>(&Tl[row * 36 + gran * 8]);
    const uint2 hi = *reinterpret_cast<const uint2*>(&Tl[row * 36 + gran * 8 + 4]);
    uint4 o; o.x = lo.x; o.y = lo.y; o.z = hi.x; o.w = hi.y;
    unsigned short* dst = xT + (((size_t)b * 25 + (sblk >> 1)) * 12 + kblk) * 4096
                        + (sblk & 1) * 2048;
    *reinterpret_cast<uint4*>(dst + t * 8) = o;
}

// ---------------------------------------------------------------------------
// GEMM1: 128o x 128s tile, BK=64 (6 steps, 32 MFMA/wave/step), identity
// uint4 staging. grid (25, 12, 4). kb order preserved -> bit-exact vs R11.
// ---------------------------------------------------------------------------
__global__ __launch_bounds__(256) void gemm1(
    const unsigned short* __restrict__ xT,   // [b][25][12][128][32]
    const unsigned short* __restrict__ wT,   // [12][12][128][32]
    unsigned short* __restrict__ qkv)        // (4,1536,3136) bf16
{
    __shared__ __align__(16) unsigned short A_lds[128 * 64];  // 2 kb-tiles
    __shared__ __align__(16) unsigned short B_lds[128 * 64];

    const int sblk = blockIdx.x;
    const int oblk = blockIdx.y;
    const int b  = blockIdx.z;
    const int t  = threadIdx.x;
    const int lane = t & 63, w = t >> 6;
    const int quad = lane >> 4, mrow = lane & 15;
    const int wm = w >> 1, wn = w & 1;

    const unsigned short* wsrc = wT + ((size_t)oblk * 12) * 4096;
    const unsigned short* xsrc = xT + (((size_t)b * 25 + sblk) * 12) * 4096;

    f32x4_t acc[4][4];
#pragma unroll
    for (int m = 0; m < 4; m++)
#pragma unroll
        for (int n = 0; n < 4; n++) acc[m][n] = (f32x4_t){0.f, 0.f, 0.f, 0.f};

    for (int kb2 = 0; kb2 < 6; kb2++) {
        const unsigned short* wp = wsrc + (size_t)kb2 * 8192;
        const unsigned short* xp = xsrc + (size_t)kb2 * 8192;
        uint4 av[4], bv[4];
#pragma unroll
        for (int i = 0; i < 4; i++) {
            av[i] = *reinterpret_cast<const uint4*>(wp + i * 2048 + t * 8);
            bv[i] = *reinterpret_cast<const uint4*>(xp + i * 2048 + t * 8);
        }

        __syncthreads();   // previous iteration's fragment reads complete
#pragma unroll
        for (int i = 0; i < 4; i++) {
            *reinterpret_cast<uint4*>(A_lds + i * 2048 + t * 8) = av[i];
            *reinterpret_cast<uint4*>(B_lds + i * 2048 + t * 8) = bv[i];
        }
        __syncthreads();

#pragma unroll
        for (int kk = 0; kk < 2; kk++) {
            bf16x8_t af[4], bf[4];
#pragma unroll
            for (int m = 0; m < 4; m++)
                af[m] = *reinterpret_cast<const bf16x8_t*>(
                    &A_lds[kk * 4096 + (wm * 64 + m * 16 + mrow) * 32 + quad * 8]);
#pragma unroll
            for (int n = 0; n < 4; n++)
                bf[n] = *reinterpret_cast<const bf16x8_t*>(
                    &B_lds[kk * 4096 + (wn * 64 + n * 16 + mrow) * 32 + quad * 8]);
#pragma unroll
            for (int m = 0; m < 4; m++)
#pragma unroll
                for (int n = 0; n < 4; n++)
                    acc[m][n] = __builtin_amdgcn_mfma_f32_16x16x32_bf16(af[m], bf[n], acc[m][n], 0, 0, 0);
        }
    }

    const int o0 = oblk * 128 + wm * 64;
    const int s0 = sblk * 128 + wn * 64;
    unsigned short* outb = qkv + (size_t)b * QKV_CH * HW;
#pragma unroll
    for (int m = 0; m < 4; m++)
#pragma unroll
        for (int n = 0; n < 4; n++) {
            const int ss = s0 + n * 16 + mrow;
            if (ss < HW) {
#pragma unroll
                for (int r = 0; r < 4; r++) {
                    const int oo = o0 + m * 16 + quad * 4 + r;
                    outb[(size_t)oo * HW + ss] = f2bf(acc[m][n][r]);
                }
            }
        }
}

// ---------------------------------------------------------------------------
// Neighborhood attention (R11 verbatim): LDS halo staging, blocked aoT out.
// ---------------------------------------------------------------------------
__global__ __launch_bounds__(256) void natt2(
    const unsigned short* __restrict__ qkv,  // (4,1536,3136) bf16
    unsigned short* __restrict__ aoT)        // [4][49][16][64][32] bf16
{
    __shared__ __align__(16) unsigned short smem[2 * 64 * SLEN]; // Kl | Vl
    unsigned short* Kl = smem;
    unsigned short* Vl = smem + 64 * SLEN;
    float* dred = reinterpret_cast<float*>(smem);  // overlays Kl after dots

    const int t = threadIdx.x, lane = t & 63, w = t >> 6;
    const int sblk = blockIdx.x;
    const int s0 = sblk * 64;
    const int s  = s0 + lane;
    const int h  = blockIdx.y, b = blockIdx.z;
    const int y  = s / WIMG, xx = s % WIMG;

    const size_t hbase = (size_t)b * QKV_CH * HW + (size_t)(h * 64) * HW;
    const unsigned short* kg = qkv + hbase + (size_t)512 * HW;
    const unsigned short* vg = qkv + hbase + (size_t)1024 * HW;

#pragma unroll
    for (int i = 0; i < 6; i++) {
        const int f = i * 256 + t;        // 0..1535
        const int d = f / 24, j = f % 24;
        int g = s0 - 64 + j * 8;
        g = min(max(g, 0), HW - 8);       // clamped slots only read by masked taps
        const uint4 k4 = *reinterpret_cast<const uint4*>(kg + (size_t)d * HW + g);
        const uint4 v4 = *reinterpret_cast<const uint4*>(vg + (size_t)d * HW + g);
        *reinterpret_cast<uint4*>(&Kl[d * SLEN + j * 8]) = k4;
        *reinterpret_cast<uint4*>(&Vl[d * SLEN + j * 8]) = v4;
    }

    int   off9[9];
    float msk[9];
#pragma unroll
    for (int ty = 0; ty < 3; ty++)
#pragma unroll
        for (int tx = 0; tx < 3; tx++) {
            const int tap = ty * 3 + tx;
            const int ny = y + ty - 1, nx = xx + tx - 1;
            const bool v = (ny >= 0) && (ny < WIMG) && (nx >= 0) && (nx < WIMG);
            off9[tap] = v ? ((ty - 1) * WIMG + (tx - 1)) : 0;
            msk[tap]  = v ? 1.f : 0.f;
        }

    __syncthreads();

    const unsigned short* qp = qkv + hbase + s;
    float dots[9];
#pragma unroll
    for (int tp = 0; tp < 9; tp++) dots[tp] = 0.f;
#pragma unroll 4
    for (int dd = 0; dd < 16; dd++) {
        const int d = w * 16 + dd;
        const float qv = bf2f(qp[(size_t)d * HW]);
        const int bi = d * SLEN + lane + 64;
#pragma unroll
        for (int tp = 0; tp < 9; tp++)
            dots[tp] += qv * bf2f(Kl[bi + off9[tp]]);
    }

    __syncthreads();
#pragma unroll
    for (int tp = 0; tp < 9; tp++) dred[(tp * 4 + w) * 64 + lane] = dots[tp];
    __syncthreads();

    float mx = -1e30f, dt[9];
#pragma unroll
    for (int tp = 0; tp < 9; tp++) {
        const float sum = dred[(tp * 4 + 0) * 64 + lane] + dred[(tp * 4 + 1) * 64 + lane] +
                          dred[(tp * 4 + 2) * 64 + lane] + dred[(tp * 4 + 3) * 64 + lane];
        dt[tp] = msk[tp] * (sum * SCALE);
        mx = fmaxf(mx, dt[tp]);
    }
    float se = 0.f, w9[9];
#pragma unroll
    for (int tp = 0; tp < 9; tp++) { w9[tp] = __expf(dt[tp] - mx); se += w9[tp]; }
    const float inv = 1.f / se;
#pragma unroll
    for (int tp = 0; tp < 9; tp++) w9[tp] *= inv * msk[tp];

    __align__(16) unsigned short ov[16];
#pragma unroll 4
    for (int dd = 0; dd < 16; dd++) {
        const int d = w * 16 + dd;
        const int bi = d * SLEN + lane + 64;
        float o = 0.f;
#pragma unroll
        for (int tp = 0; tp < 9; tp++)
            o += w9[tp] * bf2f(Vl[bi + off9[tp]]);
        ov[dd] = f2bf(o);
    }
    unsigned short* dst = aoT + (((size_t)(b * 49 + sblk)) * 16 + (h * 2 + (w >> 1))) * 2048
                        + lane * 32 + (w & 1) * 16;
    *reinterpret_cast<uint4*>(dst)     = *reinterpret_cast<const uint4*>(ov);
    *reinterpret_cast<uint4*>(dst + 8) = *reinterpret_cast<const uint4*>(ov + 8);
}

// ---------------------------------------------------------------------------
// GEMM3: 128o x 64s tile, BK=64 (8 steps, 16 MFMA/wave/step), identity
// staging from blocked aoT/wT3. grid (49, 3, 4). Bit-exact vs R11.
// ---------------------------------------------------------------------------
__global__ __launch_bounds__(256) void gemm3(
    const unsigned short* __restrict__ aoT,  // [4][49][16][64][32]
    const unsigned short* __restrict__ wT3,  // [3][16][128][32]
    const float* __restrict__ bias,          // (384)
    float* __restrict__ out)                 // (4,384,3136) f32
{
    __shared__ __align__(16) unsigned short A_lds[128 * 64];  // 2 kb-tiles
    __shared__ __align__(16) unsigned short B_lds[64 * 64];

    const int sblk = blockIdx.x;             // 0..48
    const int oblk = blockIdx.y;             // 0..2
    const int b  = blockIdx.z;
    const int t  = threadIdx.x;
    const int lane = t & 63, w = t >> 6;
    const int quad = lane >> 4, mrow = lane & 15;
    const int wm = w >> 1, wn = w & 1;       // wave: 64o x 32s quadrant

    const unsigned short* asrc = wT3 + (size_t)oblk * 16 * 4096;
    const unsigned short* bsrc = aoT + ((size_t)(b * 49 + sblk)) * 16 * 2048;

    f32x4_t acc[4][2];
#pragma unroll
    for (int m = 0; m < 4; m++)
#pragma unroll
        for (int n = 0; n < 2; n++) acc[m][n] = (f32x4_t){0.f, 0.f, 0.f, 0.f};

    for (int kb2 = 0; kb2 < 8; kb2++) {
        const unsigned short* ap = asrc + (size_t)kb2 * 8192;
        const unsigned short* bp = bsrc + (size_t)kb2 * 4096;
        uint4 av[4], bv[2];
#pragma unroll
        for (int i = 0; i < 4; i++)
            av[i] = *reinterpret_cast<const uint4*>(ap + i * 2048 + t * 8);
#pragma unroll
        for (int i = 0; i < 2; i++)
            bv[i] = *reinterpret_cast<const uint4*>(bp + i * 2048 + t * 8);

        __syncthreads();
#pragma unroll
        for (int i = 0; i < 4; i++)
            *reinterpret_cast<uint4*>(A_lds + i * 2048 + t * 8) = av[i];
#pragma unroll
        for (int i = 0; i < 2; i++)
            *reinterpret_cast<uint4*>(B_lds + i * 2048 + t * 8) = bv[i];
        __syncthreads();

#pragma unroll
        for (int kk = 0; kk < 2; kk++) {
            bf16x8_t af[4], bf[2];
#pragma unroll
            for (int m = 0; m < 4; m++)
                af[m] = *reinterpret_cast<const bf16x8_t*>(
                    &A_lds[kk * 4096 + (wm * 64 + m * 16 + mrow) * 32 + quad * 8]);
#pragma unroll
            for (int n = 0; n < 2; n++)
                bf[n] = *reinterpret_cast<const bf16x8_t*>(
                    &B_lds[kk * 2048 + (wn * 32 + n * 16 + mrow) * 32 + quad * 8]);
#pragma unroll
            for (int m = 0; m < 4; m++)
#pragma unroll
                for (int n = 0; n < 2; n++)
                    acc[m][n] = __builtin_amdgcn_mfma_f32_16x16x32_bf16(af[m], bf[n], acc[m][n], 0, 0, 0);
        }
    }

    const int o0 = oblk * 128 + wm * 64;
    const int s0 = sblk * 64 + wn * 32;
    float* outb = out + (size_t)b * 384 * HW;
#pragma unroll
    for (int m = 0; m < 4; m++)
#pragma unroll
        for (int n = 0; n < 2; n++) {
            const int ss = s0 + n * 16 + mrow;      // < 3136 always
#pragma unroll
            for (int r = 0; r < 4; r++) {
                const int oo = o0 + m * 16 + quad * 4 + r;
                outb[(size_t)oo * HW + ss] = acc[m][n][r] + bias[oo];
            }
        }
}

extern "C" void kernel_launch(void* const* d_in, const int* in_sizes, int n_in,
                              void* d_out, int out_size, void* d_ws, size_t ws_size,
                              hipStream_t stream) {
    const float* x   = (const float*)d_in[0];
    const float* Wq  = (const float*)d_in[1];
    const float* Wkv = (const float*)d_in[2];
    const float* Wo  = (const float*)d_in[3];
    const float* bo  = (const float*)d_in[4];
    float* out = (float*)d_out;

    // ws layout (bf16 elements)
    unsigned short* xT   = (unsigned short*)d_ws;                 // 4,915,200
    unsigned short* wT   = xT + (size_t)4915200;                  //   589,824
    unsigned short* wT3  = wT + (size_t)589824;                   //   196,608
    unsigned short* qkvb = wT3 + (size_t)196608;                  // 19,267,584
    unsigned short* aoT  = qkvb + (size_t)4 * QKV_CH * HW;        //  6,422,528

    cvt_w<<<dim3(384), 256, 0, stream>>>(Wq, Wkv, Wo, wT, wT3);
    cvtT_x<<<dim3(50, 12, 4), 256, 0, stream>>>(x, xT);

    gemm1<<<dim3(25, 12, 4), 256, 0, stream>>>(xT, wT, qkvb);
    natt2<<<dim3(49, 8, 4), 256, 0, stream>>>(qkvb, aoT);
    gemm3<<<dim3(49, 3, 4), 256, 0, stream>>>(aoT, wT3, bo, out);
}